// Round 15
// baseline (1608.585 us; speedup 1.0000x reference)
//
#include <hip/hip_runtime.h>
#include <math.h>

// Swin block, B=32, H=W=64, C=384, heads=12, hd=32, WS=8, SS=4.
// Round 15: 32x32x16 MFMA (2x FLOP per issue slot - r14 showed MfmaUtil ==
// static MFMA issue fraction, so raise FLOP/issue). Wave tile 64x96 (2x3
// f32x16 accs), block 128x192, BK=32, 256thr, 40KB LDS, syncthreads dbuf.
// Swizzle slot=(g+(row>>1))&3 verified conflict-free for 32-lane b128 reads.

#define ROWS_TOTAL 131072
#define NWIN_TOTAL 2048

typedef __attribute__((ext_vector_type(8))) __bf16 bf16x8;
typedef __attribute__((ext_vector_type(16))) float f32x16;
typedef __attribute__((ext_vector_type(8))) unsigned short ushort8;

__device__ __forceinline__ unsigned short f2bf(float f) {
  unsigned u = __builtin_bit_cast(unsigned, f);
  u = (u + 0x7fffu + ((u >> 16) & 1u)) >> 16;
  return (unsigned short)u;
}
__device__ __forceinline__ float bf2f(unsigned short u) {
  return __builtin_bit_cast(float, (unsigned)u << 16);
}

__device__ __forceinline__ void gload16(const void* g, void* l) {
  __builtin_amdgcn_global_load_lds(
      (const __attribute__((address_space(1))) unsigned int*)g,
      (__attribute__((address_space(3))) unsigned int*)l, 16, 0, 0);
}

__device__ __forceinline__ int gather_row(int win, int t) {
  int b = win >> 6, wi = (win >> 3) & 7, wj = win & 7;
  int gi = (wi * 8 + (t >> 3) + 4) & 63;
  int gj = (wj * 8 + (t & 7) + 4) & 63;
  return (b << 12) + (gi << 6) + gj;
}

// erf via Abramowitz-Stegun 7.1.26 (max abs err 1.5e-7)
__device__ __forceinline__ float gelu_f(float v) {
  float x = v * 0.70710678118654752f;
  float ax = fabsf(x);
  float t = 1.f / (1.f + 0.3275911f * ax);
  float poly =
      t * (0.254829592f +
           t * (-0.284496736f +
                t * (1.421413741f + t * (-1.453152027f + t * 1.061405429f))));
  float er = 1.f - poly * __expf(-x * x);
  er = copysignf(er, x);
  return 0.5f * v * (1.f + er);
}

// LDS: A[2][128 rows][32 bf16]=16KB, B[2][192][32]=24KB. 64B rows, 16B
// granules. LDS[row][slot] holds global granule (slot-(row>>1))&3; fragment
// read for granule g uses slot (g+(row>>1))&3. 32-lane b128 read pattern
// (row=lane&31): quad-group (4*row + slot)&7 enumerates all 8 -> no conflict.
#define SRC_SWZ(t_) (((((t_) & 3) - (((t_) >> 3) & 3)) & 3) << 4)

// stage one 32-deep K-step: A 2 granules/thread, B 3 granules/thread
#define STG(buf_, t_)                                                   \
  {                                                                     \
    size_t ko = (size_t)(t_) * 64;                                      \
    gload16(aS0 + ko, (char*)As + (buf_) * 8192 + tid * 16);            \
    gload16(aS1 + ko, (char*)As + (buf_) * 8192 + 4096 + tid * 16);     \
    gload16(bS0 + ko, (char*)Bs + (buf_) * 12288 + tid * 16);           \
    gload16(bS1 + ko, (char*)Bs + (buf_) * 12288 + 4096 + tid * 16);    \
    gload16(bS2 + ko, (char*)Bs + (buf_) * 12288 + 8192 + tid * 16);    \
  }

#define GEMM_DECLS()                                                    \
  f32x16 acc[2][3];                                                     \
  _Pragma("unroll") for (int i_ = 0; i_ < 2; ++i_)                      \
  _Pragma("unroll") for (int j_ = 0; j_ < 3; ++j_)                      \
      acc[i_][j_] = (f32x16)(0.f);                                      \
  int aO[2][2], bO[3][2];                                               \
  _Pragma("unroll") for (int mi_ = 0; mi_ < 2; ++mi_) {                 \
    int row_ = wr * 64 + mi_ * 32 + (lane & 31);                        \
    _Pragma("unroll") for (int sl_ = 0; sl_ < 2; ++sl_) {               \
      int g_ = sl_ * 2 + (lane >> 5);                                   \
      aO[mi_][sl_] = row_ * 32 + (((g_ + (row_ >> 1)) & 3) << 3);       \
    }                                                                   \
  }                                                                     \
  _Pragma("unroll") for (int nj_ = 0; nj_ < 3; ++nj_) {                 \
    int row_ = wc * 96 + nj_ * 32 + (lane & 31);                        \
    _Pragma("unroll") for (int sl_ = 0; sl_ < 2; ++sl_) {               \
      int g_ = sl_ * 2 + (lane >> 5);                                   \
      bO[nj_][sl_] = row_ * 32 + (((g_ + (row_ >> 1)) & 3) << 3);       \
    }                                                                   \
  }

#define GEMM_CORE(NT_)                                                  \
  {                                                                     \
    int cur = 0;                                                        \
    STG(0, 0);                                                          \
    __syncthreads();                                                    \
    for (int t = 0; t < (NT_); ++t) {                                   \
      if (t + 1 < (NT_)) STG(cur ^ 1, t + 1);                           \
      const ushort* AsC = &As[cur][0];                                  \
      const ushort* BsC = &Bs[cur][0];                                  \
      bf16x8 av[2][2], bv[3][2];                                        \
      _Pragma("unroll") for (int mi = 0; mi < 2; ++mi)                  \
      _Pragma("unroll") for (int sl = 0; sl < 2; ++sl)                  \
          av[mi][sl] = *(const bf16x8*)(AsC + aO[mi][sl]);              \
      _Pragma("unroll") for (int nj = 0; nj < 3; ++nj)                  \
      _Pragma("unroll") for (int sl = 0; sl < 2; ++sl)                  \
          bv[nj][sl] = *(const bf16x8*)(BsC + bO[nj][sl]);              \
      _Pragma("unroll") for (int sl = 0; sl < 2; ++sl)                  \
      _Pragma("unroll") for (int mi = 0; mi < 2; ++mi)                  \
      _Pragma("unroll") for (int nj = 0; nj < 3; ++nj)                  \
          acc[mi][nj] = __builtin_amdgcn_mfma_f32_32x32x16_bf16(        \
              av[mi][sl], bv[nj][sl], acc[mi][nj], 0, 0, 0);            \
      __syncthreads();                                                  \
      cur ^= 1;                                                         \
    }                                                                   \
  }

// XCD-bijective panel-fastest remap: lin -> (panel p, row-block bm)
#define GRID_SWZ(NP_)                                                   \
  int p, bm;                                                            \
  {                                                                     \
    int lin = blockIdx.y * (NP_) + blockIdx.x;                          \
    if ((gridDim.y & 7) == 0) {                                         \
      int xcd = lin & 7, q = lin >> 3;                                  \
      p = q % (NP_); bm = (q / (NP_)) * 8 + xcd;                        \
    } else { p = blockIdx.x; bm = blockIdx.y; }                         \
  }

// C/D row offset within 32-row frag: reg r, lane -> (r&3)+8*(r>>2)+4*(l>>5)
#define CD_ROW(r_, lane_) (((r_) & 3) + 8 * ((r_) >> 2) + 4 * ((lane_) >> 5))

// ---------------- weight transpose+convert: W[k][n] f32 -> Wt[n][k] bf16 ----
__global__ __launch_bounds__(256) void wprep_k(
    const float* __restrict__ qkvw, const float* __restrict__ projw,
    const float* __restrict__ fc1w, const float* __restrict__ fc2w,
    ushort* __restrict__ wq, ushort* __restrict__ wp,
    ushort* __restrict__ w1, ushort* __restrict__ w2) {
  int gid = blockIdx.x * 256 + threadIdx.x;
  const int S1 = 1152 * 384;
  const int S2 = S1 + 384 * 384;
  const int S3 = S2 + 1536 * 384;
  const int S4 = S3 + 384 * 1536;
  if (gid < S1) {
    int n = gid / 384, k = gid - n * 384;
    wq[gid] = f2bf(qkvw[(size_t)k * 1152 + n]);
  } else if (gid < S2) {
    int i = gid - S1, n = i / 384, k = i - n * 384;
    wp[i] = f2bf(projw[(size_t)k * 384 + n]);
  } else if (gid < S3) {
    int i = gid - S2, n = i / 384, k = i - n * 384;
    w1[i] = f2bf(fc1w[(size_t)k * 1536 + n]);
  } else if (gid < S4) {
    int i = gid - S3, n = i / 1536, k = i - n * 1536;
    w2[i] = f2bf(fc2w[(size_t)k * 384 + n]);
  }
}

// ---------------- fused LN: stats + apply -> bf16 ----------
__global__ __launch_bounds__(256) void ln_fused_k(
    const float* __restrict__ x, const float* __restrict__ g,
    const float* __restrict__ b, ushort* __restrict__ o) {
  int wid = threadIdx.x >> 6, lane = threadIdx.x & 63;
  int row = (blockIdx.x << 2) + wid;
  const float* p = x + (size_t)row * 384;
  float2 v[3];
  float s = 0.f, ss = 0.f;
#pragma unroll
  for (int c = 0; c < 3; ++c) {
    v[c] = *(const float2*)(p + lane * 2 + c * 128);
    s += v[c].x + v[c].y;
    ss += v[c].x * v[c].x + v[c].y * v[c].y;
  }
#pragma unroll
  for (int off = 1; off < 64; off <<= 1) {
    s += __shfl_xor(s, off);
    ss += __shfl_xor(ss, off);
  }
  float m = s * (1.f / 384.f);
  float r = rsqrtf(ss * (1.f / 384.f) - m * m + 1e-5f);
  ushort* op = o + (size_t)row * 384;
#pragma unroll
  for (int c = 0; c < 3; ++c) {
    float2 gg = *(const float2*)(g + lane * 2 + c * 128);
    float2 bb = *(const float2*)(b + lane * 2 + c * 128);
    union { ushort u[2]; unsigned w; } pk;
    pk.u[0] = f2bf((v[c].x - m) * r * gg.x + bb.x);
    pk.u[1] = f2bf((v[c].y - m) * r * gg.y + bb.y);
    *(unsigned*)(op + lane * 2 + c * 128) = pk.w;
  }
}

// ---------------- QKV GEMM -> head-contiguous bf16 q/k/v ----------------
__global__ __launch_bounds__(256) void qkv_mfma_k(
    const ushort* __restrict__ xln, const ushort* __restrict__ wq,
    const float* __restrict__ qkvb, ushort* __restrict__ qd,
    ushort* __restrict__ kd, ushort* __restrict__ vd, int wc0) {
  __shared__ __align__(16) ushort As[2][4096];
  __shared__ __align__(16) ushort Bs[2][6144];
  const int tid = threadIdx.x;
  const int lane = tid & 63;
  const int w = tid >> 6;
  const int wr = w >> 1, wc = w & 1;
  GRID_SWZ(6);
  const int n0 = p * 192;
  int r0 = tid >> 2, r1 = 64 + (tid >> 2);
  const char* aS0 = (const char*)xln +
                    (size_t)gather_row(wc0 + bm * 2 + (r0 >> 6), r0 & 63) * 768 +
                    SRC_SWZ(tid);
  const char* aS1 = (const char*)xln +
                    (size_t)gather_row(wc0 + bm * 2 + (r1 >> 6), r1 & 63) * 768 +
                    SRC_SWZ(tid);
  const char* bS0 = (const char*)wq + (size_t)(n0 + (tid >> 2)) * 768 +
                    SRC_SWZ(tid);
  const char* bS1 = (const char*)wq + (size_t)(n0 + 64 + (tid >> 2)) * 768 +
                    SRC_SWZ(tid);
  const char* bS2 = (const char*)wq + (size_t)(n0 + 128 + (tid >> 2)) * 768 +
                    SRC_SWZ(tid);
  GEMM_DECLS();
  GEMM_CORE(12);
  const float scale = 0.17677669529663687f;
#pragma unroll
  for (int mi = 0; mi < 2; ++mi) {
#pragma unroll
    for (int r = 0; r < 16; ++r) {
      int rr = wr * 64 + mi * 32 + CD_ROW(r, lane);
      int w_rel = bm * 2 + (rr >> 6), t = rr & 63;
#pragma unroll
      for (int nj = 0; nj < 3; ++nj) {
        int nc = n0 + wc * 96 + nj * 32 + (lane & 31);
        float v = acc[mi][nj][r] + qkvb[nc];
        int qi = nc / 384, rem = nc - qi * 384;
        int hh = rem >> 5, d = rem & 31;
        ushort* base = (qi == 0) ? qd : (qi == 1 ? kd : vd);
        if (qi == 0) v *= scale;
        base[(((size_t)w_rel * 12 + hh) << 11) + (t << 5) + d] = f2bf(v);
      }
    }
  }
}

// ---------------- windowed attention (fp32 compute, bf16 I/O) --------------
__global__ __launch_bounds__(128) void attn_k(
    const ushort* __restrict__ q, const ushort* __restrict__ k,
    const ushort* __restrict__ v, const float* __restrict__ rpb,
    ushort* __restrict__ ao, int wc0) {
  __shared__ __align__(16) float kbuf[2][64][32];
  __shared__ __align__(16) float vbuf[2][64][32];
  __shared__ float bias[2][232];
  __shared__ int region[64];
  const int tid = threadIdx.x;
  const int wid = tid >> 6, lane = tid & 63;
  const int w = blockIdx.x, win = wc0 + w;
  const int head = blockIdx.y * 2 + wid;
  if (tid < 64) {
    int wi = (win >> 3) & 7, wj = win & 7;
    int pi = wi * 8 + (tid >> 3), pj = wj * 8 + (tid & 7);
    int ri = pi < 56 ? 0 : (pi < 60 ? 1 : 2);
    int rj = pj < 56 ? 0 : (pj < 60 ? 1 : 2);
    region[tid] = ri * 3 + rj;
  }
  const size_t hb = ((size_t)w * 12 + head) * 2048;
  const ushort* kp = k + hb;
  const ushort* vp = v + hb;
#pragma unroll
  for (int s = 0; s < 4; ++s) {
    int f = s * 64 + lane;
    int r = f >> 2, c = (f & 3) * 8;
    ushort8 ku = *(const ushort8*)(kp + r * 32 + c);
    ushort8 vu = *(const ushort8*)(vp + r * 32 + c);
#pragma unroll
    for (int j = 0; j < 8; ++j) {
      kbuf[wid][r][c + j] = bf2f(ku[j]);
      vbuf[wid][r][c + j] = bf2f(vu[j]);
    }
  }
  for (int s = lane; s < 225; s += 64) bias[wid][s] = rpb[s * 12 + head];
  __syncthreads();
  const int i = lane;
  float qr[32];
  const ushort* qp = q + hb + (i << 5);
#pragma unroll
  for (int c = 0; c < 4; ++c) {
    ushort8 qu = *(const ushort8*)(qp + c * 8);
#pragma unroll
    for (int j = 0; j < 8; ++j) qr[c * 8 + j] = bf2f(qu[j]);
  }
  const int yi = i >> 3, xi = i & 7, regi = region[i];
  float sc[64];
  float mx = -3.0e38f;
#pragma unroll
  for (int j = 0; j < 64; ++j) {
    float a = 0.f;
#pragma unroll
    for (int c = 0; c < 32; c += 4) {
      float4 kv = *(float4*)&kbuf[wid][j][c];
      a = fmaf(qr[c], kv.x, a);
      a = fmaf(qr[c + 1], kv.y, a);
      a = fmaf(qr[c + 2], kv.z, a);
      a = fmaf(qr[c + 3], kv.w, a);
    }
    int dy = yi - (j >> 3) + 7, dx = xi - (j & 7) + 7;
    a += bias[wid][dy * 15 + dx];
    if (region[j] != regi) a -= 100.f;
    sc[j] = a;
    mx = fmaxf(mx, a);
  }
  float sum = 0.f;
#pragma unroll
  for (int j = 0; j < 64; ++j) {
    float e = __expf(sc[j] - mx);
    sc[j] = e;
    sum += e;
  }
  const float inv = 1.f / sum;
  float o[32];
#pragma unroll
  for (int c = 0; c < 32; ++c) o[c] = 0.f;
#pragma unroll
  for (int j = 0; j < 64; ++j) {
    float p = sc[j];
#pragma unroll
    for (int c = 0; c < 32; c += 4) {
      float4 vv = *(float4*)&vbuf[wid][j][c];
      o[c] = fmaf(p, vv.x, o[c]);
      o[c + 1] = fmaf(p, vv.y, o[c + 1]);
      o[c + 2] = fmaf(p, vv.z, o[c + 2]);
      o[c + 3] = fmaf(p, vv.w, o[c + 3]);
    }
  }
  ushort* op = ao + ((size_t)(w * 64 + i)) * 384 + (head << 5);
#pragma unroll
  for (int c = 0; c < 32; c += 8) {
    ushort8 pk;
#pragma unroll
    for (int j2 = 0; j2 < 8; ++j2) pk[j2] = f2bf(o[c + j2] * inv);
    *(ushort8*)(op + c) = pk;
  }
}

// ---------------- proj GEMM + unshift scatter + residual --------------------
__global__ __launch_bounds__(256) void proj_mfma_k(
    const ushort* __restrict__ ao, const ushort* __restrict__ wp,
    const float* __restrict__ pb, const float* __restrict__ x,
    float* __restrict__ x2, int wc0) {
  __shared__ __align__(16) ushort As[2][4096];
  __shared__ __align__(16) ushort Bs[2][6144];
  const int tid = threadIdx.x;
  const int lane = tid & 63;
  const int w = tid >> 6;
  const int wr = w >> 1, wc = w & 1;
  GRID_SWZ(2);
  const int n0 = p * 192;
  const char* aS0 = (const char*)ao +
                    (size_t)(bm * 128 + (tid >> 2)) * 768 + SRC_SWZ(tid);
  const char* aS1 = (const char*)ao +
                    (size_t)(bm * 128 + 64 + (tid >> 2)) * 768 + SRC_SWZ(tid);
  const char* bS0 = (const char*)wp + (size_t)(n0 + (tid >> 2)) * 768 +
                    SRC_SWZ(tid);
  const char* bS1 = (const char*)wp + (size_t)(n0 + 64 + (tid >> 2)) * 768 +
                    SRC_SWZ(tid);
  const char* bS2 = (const char*)wp + (size_t)(n0 + 128 + (tid >> 2)) * 768 +
                    SRC_SWZ(tid);
  GEMM_DECLS();
  GEMM_CORE(12);
#pragma unroll
  for (int mi = 0; mi < 2; ++mi) {
#pragma unroll
    for (int r = 0; r < 16; ++r) {
      int rr = wr * 64 + mi * 32 + CD_ROW(r, lane);
      int gl = bm * 128 + rr;
      int gr = gather_row(wc0 + (gl >> 6), gl & 63);
#pragma unroll
      for (int nj = 0; nj < 3; ++nj) {
        int nc = n0 + wc * 96 + nj * 32 + (lane & 31);
        size_t idx = (size_t)gr * 384 + nc;
        x2[idx] = acc[mi][nj][r] + pb[nc] + x[idx];
      }
    }
  }
}

// ---------------- fc1 GEMM + fast GELU -> bf16 hm ----------------
__global__ __launch_bounds__(256) void fc1_mfma_k(
    const ushort* __restrict__ x2ln, const ushort* __restrict__ w1,
    const float* __restrict__ fb, ushort* __restrict__ hm, int row0) {
  __shared__ __align__(16) ushort As[2][4096];
  __shared__ __align__(16) ushort Bs[2][6144];
  const int tid = threadIdx.x;
  const int lane = tid & 63;
  const int w = tid >> 6;
  const int wr = w >> 1, wc = w & 1;
  GRID_SWZ(8);
  const int n0 = p * 192;
  const char* aS0 = (const char*)x2ln +
                    (size_t)(row0 + bm * 128 + (tid >> 2)) * 768 +
                    SRC_SWZ(tid);
  const char* aS1 = (const char*)x2ln +
                    (size_t)(row0 + bm * 128 + 64 + (tid >> 2)) * 768 +
                    SRC_SWZ(tid);
  const char* bS0 = (const char*)w1 + (size_t)(n0 + (tid >> 2)) * 768 +
                    SRC_SWZ(tid);
  const char* bS1 = (const char*)w1 + (size_t)(n0 + 64 + (tid >> 2)) * 768 +
                    SRC_SWZ(tid);
  const char* bS2 = (const char*)w1 + (size_t)(n0 + 128 + (tid >> 2)) * 768 +
                    SRC_SWZ(tid);
  GEMM_DECLS();
  GEMM_CORE(12);
#pragma unroll
  for (int mi = 0; mi < 2; ++mi) {
#pragma unroll
    for (int r = 0; r < 16; ++r) {
      size_t lrow = (size_t)(bm * 128 + wr * 64 + mi * 32 + CD_ROW(r, lane));
#pragma unroll
      for (int nj = 0; nj < 3; ++nj) {
        int nc = n0 + wc * 96 + nj * 32 + (lane & 31);
        float v = gelu_f(acc[mi][nj][r] + fb[nc]);
        hm[lrow * 1536 + nc] = f2bf(v);
      }
    }
  }
}

// ---------------- fc2 GEMM + residual into out ----------------
__global__ __launch_bounds__(256) void fc2_mfma_k(
    const ushort* __restrict__ hm, const ushort* __restrict__ w2,
    const float* __restrict__ fb, float* __restrict__ out, int row0) {
  __shared__ __align__(16) ushort As[2][4096];
  __shared__ __align__(16) ushort Bs[2][6144];
  const int tid = threadIdx.x;
  const int lane = tid & 63;
  const int w = tid >> 6;
  const int wr = w >> 1, wc = w & 1;
  GRID_SWZ(2);
  const int n0 = p * 192;
  const char* aS0 = (const char*)hm +
                    (size_t)(bm * 128 + (tid >> 2)) * 3072 + SRC_SWZ(tid);
  const char* aS1 = (const char*)hm +
                    (size_t)(bm * 128 + 64 + (tid >> 2)) * 3072 +
                    SRC_SWZ(tid);
  const char* bS0 = (const char*)w2 + (size_t)(n0 + (tid >> 2)) * 3072 +
                    SRC_SWZ(tid);
  const char* bS1 = (const char*)w2 + (size_t)(n0 + 64 + (tid >> 2)) * 3072 +
                    SRC_SWZ(tid);
  const char* bS2 = (const char*)w2 + (size_t)(n0 + 128 + (tid >> 2)) * 3072 +
                    SRC_SWZ(tid);
  GEMM_DECLS();
  GEMM_CORE(48);
#pragma unroll
  for (int mi = 0; mi < 2; ++mi) {
#pragma unroll
    for (int r = 0; r < 16; ++r) {
      size_t grow =
          (size_t)(row0 + bm * 128 + wr * 64 + mi * 32 + CD_ROW(r, lane));
#pragma unroll
      for (int nj = 0; nj < 3; ++nj) {
        int nc = n0 + wc * 96 + nj * 32 + (lane & 31);
        size_t idx = grow * 384 + nc;
        out[idx] = out[idx] + acc[mi][nj][r] + fb[nc];
      }
    }
  }
}

extern "C" void kernel_launch(void* const* d_in, const int* in_sizes, int n_in,
                              void* d_out, int out_size, void* d_ws, size_t ws_size,
                              hipStream_t stream) {
  const float* x = (const float*)d_in[0];
  const float* qkv_w = (const float*)d_in[1];
  const float* qkv_b = (const float*)d_in[2];
  const float* proj_w = (const float*)d_in[3];
  const float* proj_b = (const float*)d_in[4];
  const float* rpb = (const float*)d_in[5];
  const float* n1g = (const float*)d_in[6];
  const float* n1b = (const float*)d_in[7];
  const float* n2g = (const float*)d_in[8];
  const float* n2b = (const float*)d_in[9];
  const float* fc1w = (const float*)d_in[10];
  const float* fc1b = (const float*)d_in[11];
  const float* fc2w = (const float*)d_in[12];
  const float* fc2b = (const float*)d_in[13];
  float* out = (float*)d_out;
  char* ws = (char*)d_ws;

  ushort* wq = (ushort*)ws;                              // [1152][384]
  ushort* wp = wq + 442368;                              // [384][384]
  ushort* w1 = wp + 147456;                              // [1536][384]
  ushort* w2 = w1 + 589824;                              // [384][1536]
  ushort* xln = (ushort*)(ws + 3538944);                 // 100663296 B
  char* scratch = ws + 3538944 + 100663296;
  size_t base = 3538944 + 100663296;
  size_t ssz = (ws_size > base) ? ws_size - base : 0;

  wprep_k<<<6912, 256, 0, stream>>>(qkv_w, proj_w, fc1w, fc2w, wq, wp, w1, w2);
  ln_fused_k<<<ROWS_TOTAL / 4, 256, 0, stream>>>(x, n1g, n1b, xln);

  // attention phase, adaptive chunking (full single pass when ws permits)
  const size_t perwin = 196608;  // q,k,v,ao bf16 (4*49152B)
  int nwc = (int)(ssz / perwin);
  if (nwc > NWIN_TOTAL) nwc = NWIN_TOTAL;
  nwc &= ~31;
  if (nwc < 32) nwc = 32;
  ushort* qd = (ushort*)scratch;
  ushort* kd = qd + (size_t)nwc * 24576;
  ushort* vd = kd + (size_t)nwc * 24576;
  ushort* ao = vd + (size_t)nwc * 24576;
  for (int wc0 = 0; wc0 < NWIN_TOTAL; wc0 += nwc) {
    int nw = (NWIN_TOTAL - wc0 < nwc) ? (NWIN_TOTAL - wc0) : nwc;
    qkv_mfma_k<<<dim3(6, nw / 2), 256, 0, stream>>>(xln, wq, qkv_b, qd, kd,
                                                    vd, wc0);
    attn_k<<<dim3(nw, 6), 128, 0, stream>>>(qd, kd, vd, rpb, ao, wc0);
    proj_mfma_k<<<dim3(2, nw / 2), 256, 0, stream>>>(ao, wp, proj_b, x, out,
                                                     wc0);
  }

  // MLP phase: M-tiles of 128 rows (1024 total), adaptive chunking
  ln_fused_k<<<ROWS_TOTAL / 4, 256, 0, stream>>>(out, n2g, n2b, xln);
  const size_t pergrp = 393216;  // 128 rows * 1536 * 2B
  int ngc = (int)(ssz / pergrp);
  if (ngc > 1024) ngc = 1024;
  ngc &= ~7;
  if (ngc < 8) ngc = 8;
  ushort* hm = (ushort*)scratch;
  for (int g0 = 0; g0 < 1024; g0 += ngc) {
    int ng = (1024 - g0 < ngc) ? (1024 - g0) : ngc;
    fc1_mfma_k<<<dim3(8, ng), 256, 0, stream>>>(xln, w1, fc1b, hm, g0 * 128);
    fc2_mfma_k<<<dim3(2, ng), 256, 0, stream>>>(hm, w2, fc2b, out, g0 * 128);
  }
}

// Round 16
// 1370.716 us; speedup vs baseline: 1.1735x; 1.1735x over previous
//
#include <hip/hip_runtime.h>
#include <math.h>

// Swin block, B=32, H=W=64, C=384, heads=12, hd=32, WS=8, SS=4.
// Round 16: r9 (best wall time, 1372us) restored verbatim, ONE fix:
// attn_k K/V LDS rows padded 32->36 floats. Old layout: scalar staging
// stores hit bank (8*(lane&3)+j)&31 -> 16-way write conflict. Padded:
// bank (4r+8c'+j)&31 covers all 32 across the wave -> conflict-free.
// Reads are row-uniform broadcasts (free) and remain 16B-aligned.

#define ROWS_TOTAL 131072
#define NWIN_TOTAL 2048

typedef __attribute__((ext_vector_type(8))) __bf16 bf16x8;
typedef __attribute__((ext_vector_type(4))) float f32x4;
typedef __attribute__((ext_vector_type(8))) unsigned short ushort8;

__device__ __forceinline__ unsigned short f2bf(float f) {
  unsigned u = __builtin_bit_cast(unsigned, f);
  u = (u + 0x7fffu + ((u >> 16) & 1u)) >> 16;
  return (unsigned short)u;
}
__device__ __forceinline__ float bf2f(unsigned short u) {
  return __builtin_bit_cast(float, (unsigned)u << 16);
}

__device__ __forceinline__ void gload16(const void* g, void* l) {
  __builtin_amdgcn_global_load_lds(
      (const __attribute__((address_space(1))) unsigned int*)g,
      (__attribute__((address_space(3))) unsigned int*)l, 16, 0, 0);
}

__device__ __forceinline__ int gather_row(int win, int t) {
  int b = win >> 6, wi = (win >> 3) & 7, wj = win & 7;
  int gi = (wi * 8 + (t >> 3) + 4) & 63;
  int gj = (wj * 8 + (t & 7) + 4) & 63;
  return (b << 12) + (gi << 6) + gj;
}

// erf via Abramowitz-Stegun 7.1.26 (max abs err 1.5e-7)
__device__ __forceinline__ float gelu_f(float v) {
  float x = v * 0.70710678118654752f;
  float ax = fabsf(x);
  float t = 1.f / (1.f + 0.3275911f * ax);
  float poly =
      t * (0.254829592f +
           t * (-0.284496736f +
                t * (1.421413741f + t * (-1.453152027f + t * 1.061405429f))));
  float er = 1.f - poly * __expf(-x * x);
  er = copysignf(er, x);
  return 0.5f * v * (1.f + er);
}

#define LGK0() asm volatile("s_waitcnt lgkmcnt(0)" ::: "memory")
#define VM4() asm volatile("s_waitcnt vmcnt(4)" ::: "memory")
#define VM0() asm volatile("s_waitcnt vmcnt(0)" ::: "memory")
#define SCB() __builtin_amdgcn_sched_barrier(0)
#define BARR() __builtin_amdgcn_s_barrier()
#define PRIO1() __builtin_amdgcn_s_setprio(1)
#define PRIO0() __builtin_amdgcn_s_setprio(0)

// LDS: A[3][256][64] bf16 (32KB/buf), B[2][192][64] (24KB/buf). 128B rows,
// 16B granule g of row r stored at slot g^(r&7); inverse applied to the
// per-lane GLOBAL source granule (gload dest linear), read applies g^(lr&7).
#define STGA_(buf_, kt_, c_)                                          \
  gload16(aSrcC[c_] + (size_t)(kt_) * 64,                             \
          (char*)As + (buf_) * 32768 + (c_) * 8192 + w * 1024)
#define STGB_(buf_, kt_, c_)                                          \
  gload16(bSrcC[c_] + (size_t)(kt_) * 64,                             \
          (char*)Bs + (buf_) * 24576 + (c_) * 8192 + w * 1024)

#define MM3(mi_, a_, bs_)                                             \
  { acc[mi_][0] = __builtin_amdgcn_mfma_f32_16x16x32_bf16(            \
        a_, bs_[0], acc[mi_][0], 0, 0, 0);                            \
    acc[mi_][1] = __builtin_amdgcn_mfma_f32_16x16x32_bf16(            \
        a_, bs_[1], acc[mi_][1], 0, 0, 0);                            \
    acc[mi_][2] = __builtin_amdgcn_mfma_f32_16x16x32_bf16(            \
        a_, bs_[2], acc[mi_][2], 0, 0, 0); }

#define GEMM_DECLS()                                                  \
  f32x4 acc[8][3];                                                    \
  _Pragma("unroll") for (int i_ = 0; i_ < 8; ++i_)                    \
  _Pragma("unroll") for (int j_ = 0; j_ < 3; ++j_)                    \
      acc[i_][j_] = (f32x4)(0.f);                                     \
  const int sl0 = ((hi) ^ (lr & 7)) * 8;                              \
  const int sl1 = ((4 + hi) ^ (lr & 7)) * 8;                          \
  const int aB0 = (wr * 128 + lr) * 64 + sl0;                         \
  const int aB1 = (wr * 128 + lr) * 64 + sl1;                         \
  const int bB0 = (wc * 48 + lr) * 64 + sl0;                          \
  const int bB1 = (wc * 48 + lr) * 64 + sl1;

#define GEMM_CORE(NT_)                                                \
  {                                                                   \
    STGA_(0, 0, 0); STGA_(0, 0, 1); STGA_(0, 0, 2); STGA_(0, 0, 3);   \
    STGB_(0, 0, 0); STGB_(0, 0, 1); STGB_(0, 0, 2);                   \
    STGA_(1, 1, 0); STGA_(1, 1, 1); STGA_(1, 1, 2); STGA_(1, 1, 3);   \
    VM4(); SCB(); BARR(); SCB();                                      \
    int curA = 0;                                                     \
    for (int t = 0; t < (NT_); ++t) {                                 \
      const int curB = t & 1;                                         \
      const ushort* AsC = (const ushort*)As + curA * 16384;           \
      const ushort* BsC = (const ushort*)Bs + curB * 12288;           \
      if (t + 1 < (NT_)) {                                            \
        STGB_(curB ^ 1, t + 1, 0);                                    \
        STGB_(curB ^ 1, t + 1, 1);                                    \
        STGB_(curB ^ 1, t + 1, 2);                                    \
      }                                                               \
      SCB();                                                          \
      bf16x8 av0, av1, av2, av3, bv0[3], bv1[3];                      \
      bv0[0] = *(const bf16x8*)(BsC + bB0);                           \
      bv0[1] = *(const bf16x8*)(BsC + bB0 + 1024);                    \
      bv0[2] = *(const bf16x8*)(BsC + bB0 + 2048);                    \
      bv1[0] = *(const bf16x8*)(BsC + bB1);                           \
      bv1[1] = *(const bf16x8*)(BsC + bB1 + 1024);                    \
      bv1[2] = *(const bf16x8*)(BsC + bB1 + 2048);                    \
      av0 = *(const bf16x8*)(AsC + aB0);                              \
      av1 = *(const bf16x8*)(AsC + aB0 + 1024);                       \
      av2 = *(const bf16x8*)(AsC + aB0 + 2048);                       \
      av3 = *(const bf16x8*)(AsC + aB0 + 3072);                       \
      LGK0(); SCB();                                                  \
      PRIO1();                                                        \
      MM3(0, av0, bv0); MM3(1, av1, bv0);                             \
      MM3(2, av2, bv0); MM3(3, av3, bv0);                             \
      PRIO0(); SCB();                                                 \
      av0 = *(const bf16x8*)(AsC + aB1);                              \
      av1 = *(const bf16x8*)(AsC + aB1 + 1024);                       \
      av2 = *(const bf16x8*)(AsC + aB1 + 2048);                       \
      av3 = *(const bf16x8*)(AsC + aB1 + 3072);                       \
      LGK0(); SCB();                                                  \
      PRIO1();                                                        \
      MM3(0, av0, bv1); MM3(1, av1, bv1);                             \
      MM3(2, av2, bv1); MM3(3, av3, bv1);                             \
      PRIO0(); SCB();                                                 \
      if (t + 2 < (NT_)) {                                            \
        int nbA = curA + 2; if (nbA >= 3) nbA -= 3;                   \
        STGA_(nbA, t + 2, 0); STGA_(nbA, t + 2, 1);                   \
        STGA_(nbA, t + 2, 2); STGA_(nbA, t + 2, 3);                   \
      }                                                               \
      SCB();                                                          \
      av0 = *(const bf16x8*)(AsC + aB0 + 4096);                       \
      av1 = *(const bf16x8*)(AsC + aB0 + 5120);                       \
      av2 = *(const bf16x8*)(AsC + aB0 + 6144);                       \
      av3 = *(const bf16x8*)(AsC + aB0 + 7168);                       \
      LGK0(); SCB();                                                  \
      PRIO1();                                                        \
      MM3(4, av0, bv0); MM3(5, av1, bv0);                             \
      MM3(6, av2, bv0); MM3(7, av3, bv0);                             \
      PRIO0(); SCB();                                                 \
      av0 = *(const bf16x8*)(AsC + aB1 + 4096);                       \
      av1 = *(const bf16x8*)(AsC + aB1 + 5120);                       \
      av2 = *(const bf16x8*)(AsC + aB1 + 6144);                       \
      av3 = *(const bf16x8*)(AsC + aB1 + 7168);                       \
      LGK0(); SCB();                                                  \
      PRIO1();                                                        \
      MM3(4, av0, bv1); MM3(5, av1, bv1);                             \
      MM3(6, av2, bv1); MM3(7, av3, bv1);                             \
      PRIO0();                                                        \
      if (t + 2 < (NT_)) { VM4(); SCB(); BARR(); SCB(); }             \
      else if (t + 1 < (NT_)) { VM0(); SCB(); BARR(); SCB(); }        \
      ++curA; if (curA == 3) curA = 0;                                \
    }                                                                 \
  }

// XCD-bijective panel-fastest remap: lin -> (panel p, row-block bm)
#define GRID_SWZ(NP_)                                                 \
  int p, bm;                                                          \
  {                                                                   \
    int lin = blockIdx.y * (NP_) + blockIdx.x;                        \
    if ((gridDim.y & 7) == 0) {                                       \
      int xcd = lin & 7, q = lin >> 3;                                \
      p = q % (NP_); bm = (q / (NP_)) * 8 + xcd;                      \
    } else { p = blockIdx.x; bm = blockIdx.y; }                       \
  }

// ---------------- weight transpose+convert: W[k][n] f32 -> Wt[n][k] bf16 ----
__global__ __launch_bounds__(256) void wprep_k(
    const float* __restrict__ qkvw, const float* __restrict__ projw,
    const float* __restrict__ fc1w, const float* __restrict__ fc2w,
    ushort* __restrict__ wq, ushort* __restrict__ wp,
    ushort* __restrict__ w1, ushort* __restrict__ w2) {
  int gid = blockIdx.x * 256 + threadIdx.x;
  const int S1 = 1152 * 384;
  const int S2 = S1 + 384 * 384;
  const int S3 = S2 + 1536 * 384;
  const int S4 = S3 + 384 * 1536;
  if (gid < S1) {
    int n = gid / 384, k = gid - n * 384;
    wq[gid] = f2bf(qkvw[(size_t)k * 1152 + n]);
  } else if (gid < S2) {
    int i = gid - S1, n = i / 384, k = i - n * 384;
    wp[i] = f2bf(projw[(size_t)k * 384 + n]);
  } else if (gid < S3) {
    int i = gid - S2, n = i / 384, k = i - n * 384;
    w1[i] = f2bf(fc1w[(size_t)k * 1536 + n]);
  } else if (gid < S4) {
    int i = gid - S3, n = i / 1536, k = i - n * 1536;
    w2[i] = f2bf(fc2w[(size_t)k * 384 + n]);
  }
}

// ---------------- fused LN: stats + apply -> bf16 ----------
__global__ __launch_bounds__(256) void ln_fused_k(
    const float* __restrict__ x, const float* __restrict__ g,
    const float* __restrict__ b, ushort* __restrict__ o) {
  int wid = threadIdx.x >> 6, lane = threadIdx.x & 63;
  int row = (blockIdx.x << 2) + wid;
  const float* p = x + (size_t)row * 384;
  float2 v[3];
  float s = 0.f, ss = 0.f;
#pragma unroll
  for (int c = 0; c < 3; ++c) {
    v[c] = *(const float2*)(p + lane * 2 + c * 128);
    s += v[c].x + v[c].y;
    ss += v[c].x * v[c].x + v[c].y * v[c].y;
  }
#pragma unroll
  for (int off = 1; off < 64; off <<= 1) {
    s += __shfl_xor(s, off);
    ss += __shfl_xor(ss, off);
  }
  float m = s * (1.f / 384.f);
  float r = rsqrtf(ss * (1.f / 384.f) - m * m + 1e-5f);
  ushort* op = o + (size_t)row * 384;
#pragma unroll
  for (int c = 0; c < 3; ++c) {
    float2 gg = *(const float2*)(g + lane * 2 + c * 128);
    float2 bb = *(const float2*)(b + lane * 2 + c * 128);
    union { ushort u[2]; unsigned w; } pk;
    pk.u[0] = f2bf((v[c].x - m) * r * gg.x + bb.x);
    pk.u[1] = f2bf((v[c].y - m) * r * gg.y + bb.y);
    *(unsigned*)(op + lane * 2 + c * 128) = pk.w;
  }
}

// ---------------- QKV GEMM: gathered xln @ WqT -> bf16 qkv ----------------
__global__ __launch_bounds__(512) void qkv_mfma_k(
    const ushort* __restrict__ xln, const ushort* __restrict__ wq,
    const float* __restrict__ qkvb, ushort* __restrict__ qd,
    ushort* __restrict__ kd, ushort* __restrict__ vd, int wc0) {
  __shared__ __align__(16) ushort As[3][16384];
  __shared__ __align__(16) ushort Bs[2][12288];
  const int tid = threadIdx.x;
  const int w = tid >> 6, lane = tid & 63;
  const int wr = w >> 2, wc = w & 3;
  const int lr = lane & 15, hi = lane >> 4;
  GRID_SWZ(6);
  const int n0 = p * 192;
  const int sg = ((tid & 7) ^ ((tid >> 3) & 7)) * 8;  // inverse-swizzled src
  const ushort* aSrcC[4];
  const ushort* bSrcC[3];
#pragma unroll
  for (int c = 0; c < 4; ++c)
    aSrcC[c] =
        xln + (size_t)gather_row(wc0 + bm * 4 + c, tid >> 3) * 384 + sg;
#pragma unroll
  for (int c = 0; c < 3; ++c)
    bSrcC[c] = wq + (size_t)(n0 + c * 64 + (tid >> 3)) * 384 + sg;
  GEMM_DECLS();
  GEMM_CORE(6);
  const float scale = 0.17677669529663687f;
#pragma unroll
  for (int mi = 0; mi < 8; ++mi) {
#pragma unroll
    for (int r = 0; r < 4; ++r) {
      int rr = wr * 128 + mi * 16 + (hi << 2) + r;
      int w_rel = bm * 4 + (rr >> 6), t = rr & 63;
#pragma unroll
      for (int nj = 0; nj < 3; ++nj) {
        int nc = n0 + wc * 48 + nj * 16 + lr;
        float v = acc[mi][nj][r] + qkvb[nc];
        int qi = nc / 384, rem = nc - qi * 384;
        int hh = rem >> 5, d = rem & 31;
        ushort* base = (qi == 0) ? qd : (qi == 1 ? kd : vd);
        if (qi == 0) v *= scale;
        base[(((size_t)w_rel * 12 + hh) << 11) + (t << 5) + d] = f2bf(v);
      }
    }
  }
}

// ---------------- windowed attention (fp32 compute, bf16 I/O) --------------
// K/V LDS rows padded to 36 floats: staging store bank (4r+8c'+j)&31 covers
// all 32 banks across the wave (was 16-way conflict at 32-float rows).
__global__ __launch_bounds__(128) void attn_k(
    const ushort* __restrict__ q, const ushort* __restrict__ k,
    const ushort* __restrict__ v, const float* __restrict__ rpb,
    ushort* __restrict__ ao, int wc0) {
  __shared__ __align__(16) float kbuf[2][64][36];
  __shared__ __align__(16) float vbuf[2][64][36];
  __shared__ float bias[2][232];
  __shared__ int region[64];
  const int tid = threadIdx.x;
  const int wid = tid >> 6, lane = tid & 63;
  const int w = blockIdx.x, win = wc0 + w;
  const int head = blockIdx.y * 2 + wid;
  if (tid < 64) {
    int wi = (win >> 3) & 7, wj = win & 7;
    int pi = wi * 8 + (tid >> 3), pj = wj * 8 + (tid & 7);
    int ri = pi < 56 ? 0 : (pi < 60 ? 1 : 2);
    int rj = pj < 56 ? 0 : (pj < 60 ? 1 : 2);
    region[tid] = ri * 3 + rj;
  }
  const size_t hb = ((size_t)w * 12 + head) * 2048;
  const ushort* kp = k + hb;
  const ushort* vp = v + hb;
#pragma unroll
  for (int s = 0; s < 4; ++s) {
    int f = s * 64 + lane;
    int r = f >> 2, c = (f & 3) * 8;
    ushort8 ku = *(const ushort8*)(kp + r * 32 + c);
    ushort8 vu = *(const ushort8*)(vp + r * 32 + c);
#pragma unroll
    for (int j = 0; j < 8; ++j) {
      kbuf[wid][r][c + j] = bf2f(ku[j]);
      vbuf[wid][r][c + j] = bf2f(vu[j]);
    }
  }
  for (int s = lane; s < 225; s += 64) bias[wid][s] = rpb[s * 12 + head];
  __syncthreads();
  const int i = lane;
  float qr[32];
  const ushort* qp = q + hb + (i << 5);
#pragma unroll
  for (int c = 0; c < 4; ++c) {
    ushort8 qu = *(const ushort8*)(qp + c * 8);
#pragma unroll
    for (int j = 0; j < 8; ++j) qr[c * 8 + j] = bf2f(qu[j]);
  }
  const int yi = i >> 3, xi = i & 7, regi = region[i];
  float sc[64];
  float mx = -3.0e38f;
#pragma unroll
  for (int j = 0; j < 64; ++j) {
    float a = 0.f;
#pragma unroll
    for (int c = 0; c < 32; c += 4) {
      float4 kv = *(float4*)&kbuf[wid][j][c];
      a = fmaf(qr[c], kv.x, a);
      a = fmaf(qr[c + 1], kv.y, a);
      a = fmaf(qr[c + 2], kv.z, a);
      a = fmaf(qr[c + 3], kv.w, a);
    }
    int dy = yi - (j >> 3) + 7, dx = xi - (j & 7) + 7;
    a += bias[wid][dy * 15 + dx];
    if (region[j] != regi) a -= 100.f;
    sc[j] = a;
    mx = fmaxf(mx, a);
  }
  float sum = 0.f;
#pragma unroll
  for (int j = 0; j < 64; ++j) {
    float e = __expf(sc[j] - mx);
    sc[j] = e;
    sum += e;
  }
  const float inv = 1.f / sum;
  float o[32];
#pragma unroll
  for (int c = 0; c < 32; ++c) o[c] = 0.f;
#pragma unroll
  for (int j = 0; j < 64; ++j) {
    float p = sc[j];
#pragma unroll
    for (int c = 0; c < 32; c += 4) {
      float4 vv = *(float4*)&vbuf[wid][j][c];
      o[c] = fmaf(p, vv.x, o[c]);
      o[c + 1] = fmaf(p, vv.y, o[c + 1]);
      o[c + 2] = fmaf(p, vv.z, o[c + 2]);
      o[c + 3] = fmaf(p, vv.w, o[c + 3]);
    }
  }
  ushort* op = ao + ((size_t)(w * 64 + i)) * 384 + (head << 5);
#pragma unroll
  for (int c = 0; c < 32; c += 8) {
    ushort8 pk;
#pragma unroll
    for (int j2 = 0; j2 < 8; ++j2) pk[j2] = f2bf(o[c + j2] * inv);
    *(ushort8*)(op + c) = pk;
  }
}

// ---------------- proj GEMM + unshift scatter + residual --------------------
__global__ __launch_bounds__(512) void proj_mfma_k(
    const ushort* __restrict__ ao, const ushort* __restrict__ wp,
    const float* __restrict__ pb, const float* __restrict__ x,
    float* __restrict__ x2, int wc0) {
  __shared__ __align__(16) ushort As[3][16384];
  __shared__ __align__(16) ushort Bs[2][12288];
  const int tid = threadIdx.x;
  const int w = tid >> 6, lane = tid & 63;
  const int wr = w >> 2, wc = w & 3;
  const int lr = lane & 15, hi = lane >> 4;
  GRID_SWZ(2);
  const int n0 = p * 192;
  const int sg = ((tid & 7) ^ ((tid >> 3) & 7)) * 8;
  const ushort* aSrcC[4];
  const ushort* bSrcC[3];
#pragma unroll
  for (int c = 0; c < 4; ++c)
    aSrcC[c] = ao + (size_t)(bm * 256 + c * 64 + (tid >> 3)) * 384 + sg;
#pragma unroll
  for (int c = 0; c < 3; ++c)
    bSrcC[c] = wp + (size_t)(n0 + c * 64 + (tid >> 3)) * 384 + sg;
  GEMM_DECLS();
  GEMM_CORE(6);
#pragma unroll
  for (int mi = 0; mi < 8; ++mi) {
#pragma unroll
    for (int r = 0; r < 4; ++r) {
      int rr = wr * 128 + mi * 16 + (hi << 2) + r;
      int gl = bm * 256 + rr;
      int gr = gather_row(wc0 + (gl >> 6), gl & 63);
#pragma unroll
      for (int nj = 0; nj < 3; ++nj) {
        int nc = n0 + wc * 48 + nj * 16 + lr;
        size_t idx = (size_t)gr * 384 + nc;
        x2[idx] = acc[mi][nj][r] + pb[nc] + x[idx];
      }
    }
  }
}

// ---------------- fc1 GEMM + fast GELU -> bf16 hm ----------------
__global__ __launch_bounds__(512) void fc1_mfma_k(
    const ushort* __restrict__ x2ln, const ushort* __restrict__ w1,
    const float* __restrict__ fb, ushort* __restrict__ hm, int row0) {
  __shared__ __align__(16) ushort As[3][16384];
  __shared__ __align__(16) ushort Bs[2][12288];
  const int tid = threadIdx.x;
  const int w = tid >> 6, lane = tid & 63;
  const int wr = w >> 2, wc = w & 3;
  const int lr = lane & 15, hi = lane >> 4;
  GRID_SWZ(8);
  const int n0 = p * 192;
  const int sg = ((tid & 7) ^ ((tid >> 3) & 7)) * 8;
  const ushort* aSrcC[4];
  const ushort* bSrcC[3];
#pragma unroll
  for (int c = 0; c < 4; ++c)
    aSrcC[c] =
        x2ln + (size_t)(row0 + bm * 256 + c * 64 + (tid >> 3)) * 384 + sg;
#pragma unroll
  for (int c = 0; c < 3; ++c)
    bSrcC[c] = w1 + (size_t)(n0 + c * 64 + (tid >> 3)) * 384 + sg;
  GEMM_DECLS();
  GEMM_CORE(6);
#pragma unroll
  for (int mi = 0; mi < 8; ++mi) {
#pragma unroll
    for (int r = 0; r < 4; ++r) {
      int rr = wr * 128 + mi * 16 + (hi << 2) + r;
      size_t lrow = (size_t)(bm * 256 + rr);
#pragma unroll
      for (int nj = 0; nj < 3; ++nj) {
        int nc = n0 + wc * 48 + nj * 16 + lr;
        float v = gelu_f(acc[mi][nj][r] + fb[nc]);
        hm[lrow * 1536 + nc] = f2bf(v);
      }
    }
  }
}

// ---------------- fc2 GEMM + residual into out ----------------
__global__ __launch_bounds__(512) void fc2_mfma_k(
    const ushort* __restrict__ hm, const ushort* __restrict__ w2,
    const float* __restrict__ fb, float* __restrict__ out, int row0) {
  __shared__ __align__(16) ushort As[3][16384];
  __shared__ __align__(16) ushort Bs[2][12288];
  const int tid = threadIdx.x;
  const int w = tid >> 6, lane = tid & 63;
  const int wr = w >> 2, wc = w & 3;
  const int lr = lane & 15, hi = lane >> 4;
  GRID_SWZ(2);
  const int n0 = p * 192;
  const int sg = ((tid & 7) ^ ((tid >> 3) & 7)) * 8;
  const ushort* aSrcC[4];
  const ushort* bSrcC[3];
#pragma unroll
  for (int c = 0; c < 4; ++c)
    aSrcC[c] = hm + (size_t)(bm * 256 + c * 64 + (tid >> 3)) * 1536 + sg;
#pragma unroll
  for (int c = 0; c < 3; ++c)
    bSrcC[c] = w2 + (size_t)(n0 + c * 64 + (tid >> 3)) * 1536 + sg;
  GEMM_DECLS();
  GEMM_CORE(24);
#pragma unroll
  for (int mi = 0; mi < 8; ++mi) {
#pragma unroll
    for (int r = 0; r < 4; ++r) {
      int rr = wr * 128 + mi * 16 + (hi << 2) + r;
      size_t grow = (size_t)(row0 + bm * 256 + rr);
#pragma unroll
      for (int nj = 0; nj < 3; ++nj) {
        int nc = n0 + wc * 48 + nj * 16 + lr;
        size_t idx = grow * 384 + nc;
        out[idx] = out[idx] + acc[mi][nj][r] + fb[nc];
      }
    }
  }
}

extern "C" void kernel_launch(void* const* d_in, const int* in_sizes, int n_in,
                              void* d_out, int out_size, void* d_ws, size_t ws_size,
                              hipStream_t stream) {
  const float* x = (const float*)d_in[0];
  const float* qkv_w = (const float*)d_in[1];
  const float* qkv_b = (const float*)d_in[2];
  const float* proj_w = (const float*)d_in[3];
  const float* proj_b = (const float*)d_in[4];
  const float* rpb = (const float*)d_in[5];
  const float* n1g = (const float*)d_in[6];
  const float* n1b = (const float*)d_in[7];
  const float* n2g = (const float*)d_in[8];
  const float* n2b = (const float*)d_in[9];
  const float* fc1w = (const float*)d_in[10];
  const float* fc1b = (const float*)d_in[11];
  const float* fc2w = (const float*)d_in[12];
  const float* fc2b = (const float*)d_in[13];
  float* out = (float*)d_out;
  char* ws = (char*)d_ws;

  ushort* wq = (ushort*)ws;                              // [1152][384]
  ushort* wp = wq + 442368;                              // [384][384]
  ushort* w1 = wp + 147456;                              // [1536][384]
  ushort* w2 = w1 + 589824;                              // [384][1536]
  ushort* xln = (ushort*)(ws + 3538944);                 // 100663296 B
  char* scratch = ws + 3538944 + 100663296;
  size_t base = 3538944 + 100663296;
  size_t ssz = (ws_size > base) ? ws_size - base : 0;

  wprep_k<<<6912, 256, 0, stream>>>(qkv_w, proj_w, fc1w, fc2w, wq, wp, w1, w2);
  ln_fused_k<<<ROWS_TOTAL / 4, 256, 0, stream>>>(x, n1g, n1b, xln);

  // attention phase, chunked over windows (32-window granularity)
  const size_t perwin = 196608;  // q,k,v,ao bf16 (4*49152B)
  int nwc = (int)(ssz / perwin);
  if (nwc > NWIN_TOTAL) nwc = NWIN_TOTAL;
  nwc &= ~31;
  if (nwc < 32) nwc = 32;
  ushort* qd = (ushort*)scratch;
  ushort* kd = qd + (size_t)nwc * 24576;
  ushort* vd = kd + (size_t)nwc * 24576;
  ushort* ao = vd + (size_t)nwc * 24576;
  for (int wc0 = 0; wc0 < NWIN_TOTAL; wc0 += nwc) {
    int nw = (NWIN_TOTAL - wc0 < nwc) ? (NWIN_TOTAL - wc0) : nwc;
    qkv_mfma_k<<<dim3(6, nw / 4), 512, 0, stream>>>(xln, wq, qkv_b, qd, kd,
                                                    vd, wc0);
    attn_k<<<dim3(nw, 6), 128, 0, stream>>>(qd, kd, vd, rpb, ao, wc0);
    proj_mfma_k<<<dim3(2, nw / 4), 512, 0, stream>>>(ao, wp, proj_b, x, out,
                                                     wc0);
  }

  // MLP phase: groups of 256 rows (512 total)
  ln_fused_k<<<ROWS_TOTAL / 4, 256, 0, stream>>>(out, n2g, n2b, xln);
  const size_t pergrp = 786432;  // 256 rows * 1536 * 2B
  int ngc = (int)(ssz / pergrp);
  if (ngc > 512) ngc = 512;
  ngc &= ~7;
  if (ngc < 8) ngc = 8;
  ushort* hm = (ushort*)scratch;
  for (int g0 = 0; g0 < 512; g0 += ngc) {
    int ng = (512 - g0 < ngc) ? (512 - g0) : ngc;
    fc1_mfma_k<<<dim3(8, ng), 512, 0, stream>>>(xln, w1, fc1b, hm, g0 * 256);
    fc2_mfma_k<<<dim3(2, ng), 512, 0, stream>>>(hm, w2, fc2b, out, g0 * 256);
  }
}

// Round 17
// 1363.310 us; speedup vs baseline: 1.1799x; 1.0054x over previous
//
#include <hip/hip_runtime.h>
#include <math.h>

// Swin block, B=32, H=W=64, C=384, heads=12, hd=32, WS=8, SS=4.
// Round 17: r16 (best, 1370us) + coalesced tiled weight transpose (wprep was
// fully uncoalesced strided reads, ~16x overfetch). Everything else verbatim.

#define ROWS_TOTAL 131072
#define NWIN_TOTAL 2048

typedef __attribute__((ext_vector_type(8))) __bf16 bf16x8;
typedef __attribute__((ext_vector_type(4))) float f32x4;
typedef __attribute__((ext_vector_type(8))) unsigned short ushort8;

__device__ __forceinline__ unsigned short f2bf(float f) {
  unsigned u = __builtin_bit_cast(unsigned, f);
  u = (u + 0x7fffu + ((u >> 16) & 1u)) >> 16;
  return (unsigned short)u;
}
__device__ __forceinline__ float bf2f(unsigned short u) {
  return __builtin_bit_cast(float, (unsigned)u << 16);
}

__device__ __forceinline__ void gload16(const void* g, void* l) {
  __builtin_amdgcn_global_load_lds(
      (const __attribute__((address_space(1))) unsigned int*)g,
      (__attribute__((address_space(3))) unsigned int*)l, 16, 0, 0);
}

__device__ __forceinline__ int gather_row(int win, int t) {
  int b = win >> 6, wi = (win >> 3) & 7, wj = win & 7;
  int gi = (wi * 8 + (t >> 3) + 4) & 63;
  int gj = (wj * 8 + (t & 7) + 4) & 63;
  return (b << 12) + (gi << 6) + gj;
}

// erf via Abramowitz-Stegun 7.1.26 (max abs err 1.5e-7)
__device__ __forceinline__ float gelu_f(float v) {
  float x = v * 0.70710678118654752f;
  float ax = fabsf(x);
  float t = 1.f / (1.f + 0.3275911f * ax);
  float poly =
      t * (0.254829592f +
           t * (-0.284496736f +
                t * (1.421413741f + t * (-1.453152027f + t * 1.061405429f))));
  float er = 1.f - poly * __expf(-x * x);
  er = copysignf(er, x);
  return 0.5f * v * (1.f + er);
}

#define LGK0() asm volatile("s_waitcnt lgkmcnt(0)" ::: "memory")
#define VM4() asm volatile("s_waitcnt vmcnt(4)" ::: "memory")
#define VM0() asm volatile("s_waitcnt vmcnt(0)" ::: "memory")
#define SCB() __builtin_amdgcn_sched_barrier(0)
#define BARR() __builtin_amdgcn_s_barrier()
#define PRIO1() __builtin_amdgcn_s_setprio(1)
#define PRIO0() __builtin_amdgcn_s_setprio(0)

// LDS: A[3][256][64] bf16 (32KB/buf), B[2][192][64] (24KB/buf). 128B rows,
// 16B granule g of row r stored at slot g^(r&7); inverse applied to the
// per-lane GLOBAL source granule (gload dest linear), read applies g^(lr&7).
#define STGA_(buf_, kt_, c_)                                          \
  gload16(aSrcC[c_] + (size_t)(kt_) * 64,                             \
          (char*)As + (buf_) * 32768 + (c_) * 8192 + w * 1024)
#define STGB_(buf_, kt_, c_)                                          \
  gload16(bSrcC[c_] + (size_t)(kt_) * 64,                             \
          (char*)Bs + (buf_) * 24576 + (c_) * 8192 + w * 1024)

#define MM3(mi_, a_, bs_)                                             \
  { acc[mi_][0] = __builtin_amdgcn_mfma_f32_16x16x32_bf16(            \
        a_, bs_[0], acc[mi_][0], 0, 0, 0);                            \
    acc[mi_][1] = __builtin_amdgcn_mfma_f32_16x16x32_bf16(            \
        a_, bs_[1], acc[mi_][1], 0, 0, 0);                            \
    acc[mi_][2] = __builtin_amdgcn_mfma_f32_16x16x32_bf16(            \
        a_, bs_[2], acc[mi_][2], 0, 0, 0); }

#define GEMM_DECLS()                                                  \
  f32x4 acc[8][3];                                                    \
  _Pragma("unroll") for (int i_ = 0; i_ < 8; ++i_)                    \
  _Pragma("unroll") for (int j_ = 0; j_ < 3; ++j_)                    \
      acc[i_][j_] = (f32x4)(0.f);                                     \
  const int sl0 = ((hi) ^ (lr & 7)) * 8;                              \
  const int sl1 = ((4 + hi) ^ (lr & 7)) * 8;                          \
  const int aB0 = (wr * 128 + lr) * 64 + sl0;                         \
  const int aB1 = (wr * 128 + lr) * 64 + sl1;                         \
  const int bB0 = (wc * 48 + lr) * 64 + sl0;                          \
  const int bB1 = (wc * 48 + lr) * 64 + sl1;

#define GEMM_CORE(NT_)                                                \
  {                                                                   \
    STGA_(0, 0, 0); STGA_(0, 0, 1); STGA_(0, 0, 2); STGA_(0, 0, 3);   \
    STGB_(0, 0, 0); STGB_(0, 0, 1); STGB_(0, 0, 2);                   \
    STGA_(1, 1, 0); STGA_(1, 1, 1); STGA_(1, 1, 2); STGA_(1, 1, 3);   \
    VM4(); SCB(); BARR(); SCB();                                      \
    int curA = 0;                                                     \
    for (int t = 0; t < (NT_); ++t) {                                 \
      const int curB = t & 1;                                         \
      const ushort* AsC = (const ushort*)As + curA * 16384;           \
      const ushort* BsC = (const ushort*)Bs + curB * 12288;           \
      if (t + 1 < (NT_)) {                                            \
        STGB_(curB ^ 1, t + 1, 0);                                    \
        STGB_(curB ^ 1, t + 1, 1);                                    \
        STGB_(curB ^ 1, t + 1, 2);                                    \
      }                                                               \
      SCB();                                                          \
      bf16x8 av0, av1, av2, av3, bv0[3], bv1[3];                      \
      bv0[0] = *(const bf16x8*)(BsC + bB0);                           \
      bv0[1] = *(const bf16x8*)(BsC + bB0 + 1024);                    \
      bv0[2] = *(const bf16x8*)(BsC + bB0 + 2048);                    \
      bv1[0] = *(const bf16x8*)(BsC + bB1);                           \
      bv1[1] = *(const bf16x8*)(BsC + bB1 + 1024);                    \
      bv1[2] = *(const bf16x8*)(BsC + bB1 + 2048);                    \
      av0 = *(const bf16x8*)(AsC + aB0);                              \
      av1 = *(const bf16x8*)(AsC + aB0 + 1024);                       \
      av2 = *(const bf16x8*)(AsC + aB0 + 2048);                       \
      av3 = *(const bf16x8*)(AsC + aB0 + 3072);                       \
      LGK0(); SCB();                                                  \
      PRIO1();                                                        \
      MM3(0, av0, bv0); MM3(1, av1, bv0);                             \
      MM3(2, av2, bv0); MM3(3, av3, bv0);                             \
      PRIO0(); SCB();                                                 \
      av0 = *(const bf16x8*)(AsC + aB1);                              \
      av1 = *(const bf16x8*)(AsC + aB1 + 1024);                       \
      av2 = *(const bf16x8*)(AsC + aB1 + 2048);                       \
      av3 = *(const bf16x8*)(AsC + aB1 + 3072);                       \
      LGK0(); SCB();                                                  \
      PRIO1();                                                        \
      MM3(0, av0, bv1); MM3(1, av1, bv1);                             \
      MM3(2, av2, bv1); MM3(3, av3, bv1);                             \
      PRIO0(); SCB();                                                 \
      if (t + 2 < (NT_)) {                                            \
        int nbA = curA + 2; if (nbA >= 3) nbA -= 3;                   \
        STGA_(nbA, t + 2, 0); STGA_(nbA, t + 2, 1);                   \
        STGA_(nbA, t + 2, 2); STGA_(nbA, t + 2, 3);                   \
      }                                                               \
      SCB();                                                          \
      av0 = *(const bf16x8*)(AsC + aB0 + 4096);                       \
      av1 = *(const bf16x8*)(AsC + aB0 + 5120);                       \
      av2 = *(const bf16x8*)(AsC + aB0 + 6144);                       \
      av3 = *(const bf16x8*)(AsC + aB0 + 7168);                       \
      LGK0(); SCB();                                                  \
      PRIO1();                                                        \
      MM3(4, av0, bv0); MM3(5, av1, bv0);                             \
      MM3(6, av2, bv0); MM3(7, av3, bv0);                             \
      PRIO0(); SCB();                                                 \
      av0 = *(const bf16x8*)(AsC + aB1 + 4096);                       \
      av1 = *(const bf16x8*)(AsC + aB1 + 5120);                       \
      av2 = *(const bf16x8*)(AsC + aB1 + 6144);                       \
      av3 = *(const bf16x8*)(AsC + aB1 + 7168);                       \
      LGK0(); SCB();                                                  \
      PRIO1();                                                        \
      MM3(4, av0, bv1); MM3(5, av1, bv1);                             \
      MM3(6, av2, bv1); MM3(7, av3, bv1);                             \
      PRIO0();                                                        \
      if (t + 2 < (NT_)) { VM4(); SCB(); BARR(); SCB(); }             \
      else if (t + 1 < (NT_)) { VM0(); SCB(); BARR(); SCB(); }        \
      ++curA; if (curA == 3) curA = 0;                                \
    }                                                                 \
  }

// XCD-bijective panel-fastest remap: lin -> (panel p, row-block bm)
#define GRID_SWZ(NP_)                                                 \
  int p, bm;                                                          \
  {                                                                   \
    int lin = blockIdx.y * (NP_) + blockIdx.x;                        \
    if ((gridDim.y & 7) == 0) {                                       \
      int xcd = lin & 7, q = lin >> 3;                                \
      p = q % (NP_); bm = (q / (NP_)) * 8 + xcd;                      \
    } else { p = blockIdx.x; bm = blockIdx.y; }                       \
  }

// ---------------- tiled weight transpose: W[k][n] f32 -> Wt[n][k] bf16 ------
// 64x64 tiles, coalesced reads along n, LDS[64][65] (transposed read-out is
// bank (k+n)&31 -> 2-way, free), coalesced bf16 writes along k. 432 tiles.
__global__ __launch_bounds__(256) void wprep_t_k(
    const float* __restrict__ qkvw, const float* __restrict__ projw,
    const float* __restrict__ fc1w, const float* __restrict__ fc2w,
    ushort* __restrict__ wq, ushort* __restrict__ wp,
    ushort* __restrict__ w1, ushort* __restrict__ w2) {
  __shared__ float tile[64][65];
  int t = blockIdx.x;
  const float* src;
  ushort* dst;
  int K, N, ntn;
  if (t < 108) { src = qkvw; dst = wq; K = 384; N = 1152; ntn = 18; }
  else if (t < 144) { t -= 108; src = projw; dst = wp; K = 384; N = 384; ntn = 6; }
  else if (t < 288) { t -= 144; src = fc1w; dst = w1; K = 384; N = 1536; ntn = 24; }
  else { t -= 288; src = fc2w; dst = w2; K = 1536; N = 384; ntn = 6; }
  const int tid = threadIdx.x;
  const int k0 = (t / ntn) * 64, n0 = (t % ntn) * 64;
  const int rr = tid >> 6, cc = tid & 63;
#pragma unroll
  for (int i = 0; i < 16; ++i) {
    int r = i * 4 + rr;
    tile[r][cc] = src[(size_t)(k0 + r) * N + n0 + cc];
  }
  __syncthreads();
#pragma unroll
  for (int i = 0; i < 16; ++i) {
    int n = i * 4 + rr;
    dst[(size_t)(n0 + n) * K + k0 + cc] = f2bf(tile[cc][n]);
  }
}

// ---------------- fused LN: stats + apply -> bf16 ----------
__global__ __launch_bounds__(256) void ln_fused_k(
    const float* __restrict__ x, const float* __restrict__ g,
    const float* __restrict__ b, ushort* __restrict__ o) {
  int wid = threadIdx.x >> 6, lane = threadIdx.x & 63;
  int row = (blockIdx.x << 2) + wid;
  const float* p = x + (size_t)row * 384;
  float2 v[3];
  float s = 0.f, ss = 0.f;
#pragma unroll
  for (int c = 0; c < 3; ++c) {
    v[c] = *(const float2*)(p + lane * 2 + c * 128);
    s += v[c].x + v[c].y;
    ss += v[c].x * v[c].x + v[c].y * v[c].y;
  }
#pragma unroll
  for (int off = 1; off < 64; off <<= 1) {
    s += __shfl_xor(s, off);
    ss += __shfl_xor(ss, off);
  }
  float m = s * (1.f / 384.f);
  float r = rsqrtf(ss * (1.f / 384.f) - m * m + 1e-5f);
  ushort* op = o + (size_t)row * 384;
#pragma unroll
  for (int c = 0; c < 3; ++c) {
    float2 gg = *(const float2*)(g + lane * 2 + c * 128);
    float2 bb = *(const float2*)(b + lane * 2 + c * 128);
    union { ushort u[2]; unsigned w; } pk;
    pk.u[0] = f2bf((v[c].x - m) * r * gg.x + bb.x);
    pk.u[1] = f2bf((v[c].y - m) * r * gg.y + bb.y);
    *(unsigned*)(op + lane * 2 + c * 128) = pk.w;
  }
}

// ---------------- QKV GEMM: gathered xln @ WqT -> bf16 qkv ----------------
__global__ __launch_bounds__(512) void qkv_mfma_k(
    const ushort* __restrict__ xln, const ushort* __restrict__ wq,
    const float* __restrict__ qkvb, ushort* __restrict__ qd,
    ushort* __restrict__ kd, ushort* __restrict__ vd, int wc0) {
  __shared__ __align__(16) ushort As[3][16384];
  __shared__ __align__(16) ushort Bs[2][12288];
  const int tid = threadIdx.x;
  const int w = tid >> 6, lane = tid & 63;
  const int wr = w >> 2, wc = w & 3;
  const int lr = lane & 15, hi = lane >> 4;
  GRID_SWZ(6);
  const int n0 = p * 192;
  const int sg = ((tid & 7) ^ ((tid >> 3) & 7)) * 8;  // inverse-swizzled src
  const ushort* aSrcC[4];
  const ushort* bSrcC[3];
#pragma unroll
  for (int c = 0; c < 4; ++c)
    aSrcC[c] =
        xln + (size_t)gather_row(wc0 + bm * 4 + c, tid >> 3) * 384 + sg;
#pragma unroll
  for (int c = 0; c < 3; ++c)
    bSrcC[c] = wq + (size_t)(n0 + c * 64 + (tid >> 3)) * 384 + sg;
  GEMM_DECLS();
  GEMM_CORE(6);
  const float scale = 0.17677669529663687f;
#pragma unroll
  for (int mi = 0; mi < 8; ++mi) {
#pragma unroll
    for (int r = 0; r < 4; ++r) {
      int rr = wr * 128 + mi * 16 + (hi << 2) + r;
      int w_rel = bm * 4 + (rr >> 6), t = rr & 63;
#pragma unroll
      for (int nj = 0; nj < 3; ++nj) {
        int nc = n0 + wc * 48 + nj * 16 + lr;
        float v = acc[mi][nj][r] + qkvb[nc];
        int qi = nc / 384, rem = nc - qi * 384;
        int hh = rem >> 5, d = rem & 31;
        ushort* base = (qi == 0) ? qd : (qi == 1 ? kd : vd);
        if (qi == 0) v *= scale;
        base[(((size_t)w_rel * 12 + hh) << 11) + (t << 5) + d] = f2bf(v);
      }
    }
  }
}

// ---------------- windowed attention (fp32 compute, bf16 I/O) --------------
__global__ __launch_bounds__(128) void attn_k(
    const ushort* __restrict__ q, const ushort* __restrict__ k,
    const ushort* __restrict__ v, const float* __restrict__ rpb,
    ushort* __restrict__ ao, int wc0) {
  __shared__ __align__(16) float kbuf[2][64][36];
  __shared__ __align__(16) float vbuf[2][64][36];
  __shared__ float bias[2][232];
  __shared__ int region[64];
  const int tid = threadIdx.x;
  const int wid = tid >> 6, lane = tid & 63;
  const int w = blockIdx.x, win = wc0 + w;
  const int head = blockIdx.y * 2 + wid;
  if (tid < 64) {
    int wi = (win >> 3) & 7, wj = win & 7;
    int pi = wi * 8 + (tid >> 3), pj = wj * 8 + (tid & 7);
    int ri = pi < 56 ? 0 : (pi < 60 ? 1 : 2);
    int rj = pj < 56 ? 0 : (pj < 60 ? 1 : 2);
    region[tid] = ri * 3 + rj;
  }
  const size_t hb = ((size_t)w * 12 + head) * 2048;
  const ushort* kp = k + hb;
  const ushort* vp = v + hb;
#pragma unroll
  for (int s = 0; s < 4; ++s) {
    int f = s * 64 + lane;
    int r = f >> 2, c = (f & 3) * 8;
    ushort8 ku = *(const ushort8*)(kp + r * 32 + c);
    ushort8 vu = *(const ushort8*)(vp + r * 32 + c);
#pragma unroll
    for (int j = 0; j < 8; ++j) {
      kbuf[wid][r][c + j] = bf2f(ku[j]);
      vbuf[wid][r][c + j] = bf2f(vu[j]);
    }
  }
  for (int s = lane; s < 225; s += 64) bias[wid][s] = rpb[s * 12 + head];
  __syncthreads();
  const int i = lane;
  float qr[32];
  const ushort* qp = q + hb + (i << 5);
#pragma unroll
  for (int c = 0; c < 4; ++c) {
    ushort8 qu = *(const ushort8*)(qp + c * 8);
#pragma unroll
    for (int j = 0; j < 8; ++j) qr[c * 8 + j] = bf2f(qu[j]);
  }
  const int yi = i >> 3, xi = i & 7, regi = region[i];
  float sc[64];
  float mx = -3.0e38f;
#pragma unroll
  for (int j = 0; j < 64; ++j) {
    float a = 0.f;
#pragma unroll
    for (int c = 0; c < 32; c += 4) {
      float4 kv = *(float4*)&kbuf[wid][j][c];
      a = fmaf(qr[c], kv.x, a);
      a = fmaf(qr[c + 1], kv.y, a);
      a = fmaf(qr[c + 2], kv.z, a);
      a = fmaf(qr[c + 3], kv.w, a);
    }
    int dy = yi - (j >> 3) + 7, dx = xi - (j & 7) + 7;
    a += bias[wid][dy * 15 + dx];
    if (region[j] != regi) a -= 100.f;
    sc[j] = a;
    mx = fmaxf(mx, a);
  }
  float sum = 0.f;
#pragma unroll
  for (int j = 0; j < 64; ++j) {
    float e = __expf(sc[j] - mx);
    sc[j] = e;
    sum += e;
  }
  const float inv = 1.f / sum;
  float o[32];
#pragma unroll
  for (int c = 0; c < 32; ++c) o[c] = 0.f;
#pragma unroll
  for (int j = 0; j < 64; ++j) {
    float p = sc[j];
#pragma unroll
    for (int c = 0; c < 32; c += 4) {
      float4 vv = *(float4*)&vbuf[wid][j][c];
      o[c] = fmaf(p, vv.x, o[c]);
      o[c + 1] = fmaf(p, vv.y, o[c + 1]);
      o[c + 2] = fmaf(p, vv.z, o[c + 2]);
      o[c + 3] = fmaf(p, vv.w, o[c + 3]);
    }
  }
  ushort* op = ao + ((size_t)(w * 64 + i)) * 384 + (head << 5);
#pragma unroll
  for (int c = 0; c < 32; c += 8) {
    ushort8 pk;
#pragma unroll
    for (int j2 = 0; j2 < 8; ++j2) pk[j2] = f2bf(o[c + j2] * inv);
    *(ushort8*)(op + c) = pk;
  }
}

// ---------------- proj GEMM + unshift scatter + residual --------------------
__global__ __launch_bounds__(512) void proj_mfma_k(
    const ushort* __restrict__ ao, const ushort* __restrict__ wp,
    const float* __restrict__ pb, const float* __restrict__ x,
    float* __restrict__ x2, int wc0) {
  __shared__ __align__(16) ushort As[3][16384];
  __shared__ __align__(16) ushort Bs[2][12288];
  const int tid = threadIdx.x;
  const int w = tid >> 6, lane = tid & 63;
  const int wr = w >> 2, wc = w & 3;
  const int lr = lane & 15, hi = lane >> 4;
  GRID_SWZ(2);
  const int n0 = p * 192;
  const int sg = ((tid & 7) ^ ((tid >> 3) & 7)) * 8;
  const ushort* aSrcC[4];
  const ushort* bSrcC[3];
#pragma unroll
  for (int c = 0; c < 4; ++c)
    aSrcC[c] = ao + (size_t)(bm * 256 + c * 64 + (tid >> 3)) * 384 + sg;
#pragma unroll
  for (int c = 0; c < 3; ++c)
    bSrcC[c] = wp + (size_t)(n0 + c * 64 + (tid >> 3)) * 384 + sg;
  GEMM_DECLS();
  GEMM_CORE(6);
#pragma unroll
  for (int mi = 0; mi < 8; ++mi) {
#pragma unroll
    for (int r = 0; r < 4; ++r) {
      int rr = wr * 128 + mi * 16 + (hi << 2) + r;
      int gl = bm * 256 + rr;
      int gr = gather_row(wc0 + (gl >> 6), gl & 63);
#pragma unroll
      for (int nj = 0; nj < 3; ++nj) {
        int nc = n0 + wc * 48 + nj * 16 + lr;
        size_t idx = (size_t)gr * 384 + nc;
        x2[idx] = acc[mi][nj][r] + pb[nc] + x[idx];
      }
    }
  }
}

// ---------------- fc1 GEMM + fast GELU -> bf16 hm ----------------
__global__ __launch_bounds__(512) void fc1_mfma_k(
    const ushort* __restrict__ x2ln, const ushort* __restrict__ w1,
    const float* __restrict__ fb, ushort* __restrict__ hm, int row0) {
  __shared__ __align__(16) ushort As[3][16384];
  __shared__ __align__(16) ushort Bs[2][12288];
  const int tid = threadIdx.x;
  const int w = tid >> 6, lane = tid & 63;
  const int wr = w >> 2, wc = w & 3;
  const int lr = lane & 15, hi = lane >> 4;
  GRID_SWZ(8);
  const int n0 = p * 192;
  const int sg = ((tid & 7) ^ ((tid >> 3) & 7)) * 8;
  const ushort* aSrcC[4];
  const ushort* bSrcC[3];
#pragma unroll
  for (int c = 0; c < 4; ++c)
    aSrcC[c] =
        x2ln + (size_t)(row0 + bm * 256 + c * 64 + (tid >> 3)) * 384 + sg;
#pragma unroll
  for (int c = 0; c < 3; ++c)
    bSrcC[c] = w1 + (size_t)(n0 + c * 64 + (tid >> 3)) * 384 + sg;
  GEMM_DECLS();
  GEMM_CORE(6);
#pragma unroll
  for (int mi = 0; mi < 8; ++mi) {
#pragma unroll
    for (int r = 0; r < 4; ++r) {
      int rr = wr * 128 + mi * 16 + (hi << 2) + r;
      size_t lrow = (size_t)(bm * 256 + rr);
#pragma unroll
      for (int nj = 0; nj < 3; ++nj) {
        int nc = n0 + wc * 48 + nj * 16 + lr;
        float v = gelu_f(acc[mi][nj][r] + fb[nc]);
        hm[lrow * 1536 + nc] = f2bf(v);
      }
    }
  }
}

// ---------------- fc2 GEMM + residual into out ----------------
__global__ __launch_bounds__(512) void fc2_mfma_k(
    const ushort* __restrict__ hm, const ushort* __restrict__ w2,
    const float* __restrict__ fb, float* __restrict__ out, int row0) {
  __shared__ __align__(16) ushort As[3][16384];
  __shared__ __align__(16) ushort Bs[2][12288];
  const int tid = threadIdx.x;
  const int w = tid >> 6, lane = tid & 63;
  const int wr = w >> 2, wc = w & 3;
  const int lr = lane & 15, hi = lane >> 4;
  GRID_SWZ(2);
  const int n0 = p * 192;
  const int sg = ((tid & 7) ^ ((tid >> 3) & 7)) * 8;
  const ushort* aSrcC[4];
  const ushort* bSrcC[3];
#pragma unroll
  for (int c = 0; c < 4; ++c)
    aSrcC[c] = hm + (size_t)(bm * 256 + c * 64 + (tid >> 3)) * 1536 + sg;
#pragma unroll
  for (int c = 0; c < 3; ++c)
    bSrcC[c] = w2 + (size_t)(n0 + c * 64 + (tid >> 3)) * 1536 + sg;
  GEMM_DECLS();
  GEMM_CORE(24);
#pragma unroll
  for (int mi = 0; mi < 8; ++mi) {
#pragma unroll
    for (int r = 0; r < 4; ++r) {
      int rr = wr * 128 + mi * 16 + (hi << 2) + r;
      size_t grow = (size_t)(row0 + bm * 256 + rr);
#pragma unroll
      for (int nj = 0; nj < 3; ++nj) {
        int nc = n0 + wc * 48 + nj * 16 + lr;
        size_t idx = grow * 384 + nc;
        out[idx] = out[idx] + acc[mi][nj][r] + fb[nc];
      }
    }
  }
}

extern "C" void kernel_launch(void* const* d_in, const int* in_sizes, int n_in,
                              void* d_out, int out_size, void* d_ws, size_t ws_size,
                              hipStream_t stream) {
  const float* x = (const float*)d_in[0];
  const float* qkv_w = (const float*)d_in[1];
  const float* qkv_b = (const float*)d_in[2];
  const float* proj_w = (const float*)d_in[3];
  const float* proj_b = (const float*)d_in[4];
  const float* rpb = (const float*)d_in[5];
  const float* n1g = (const float*)d_in[6];
  const float* n1b = (const float*)d_in[7];
  const float* n2g = (const float*)d_in[8];
  const float* n2b = (const float*)d_in[9];
  const float* fc1w = (const float*)d_in[10];
  const float* fc1b = (const float*)d_in[11];
  const float* fc2w = (const float*)d_in[12];
  const float* fc2b = (const float*)d_in[13];
  float* out = (float*)d_out;
  char* ws = (char*)d_ws;

  ushort* wq = (ushort*)ws;                              // [1152][384]
  ushort* wp = wq + 442368;                              // [384][384]
  ushort* w1 = wp + 147456;                              // [1536][384]
  ushort* w2 = w1 + 589824;                              // [384][1536]
  ushort* xln = (ushort*)(ws + 3538944);                 // 100663296 B
  char* scratch = ws + 3538944 + 100663296;
  size_t base = 3538944 + 100663296;
  size_t ssz = (ws_size > base) ? ws_size - base : 0;

  wprep_t_k<<<432, 256, 0, stream>>>(qkv_w, proj_w, fc1w, fc2w, wq, wp, w1,
                                     w2);
  ln_fused_k<<<ROWS_TOTAL / 4, 256, 0, stream>>>(x, n1g, n1b, xln);

  // attention phase, chunked over windows (32-window granularity)
  const size_t perwin = 196608;  // q,k,v,ao bf16 (4*49152B)
  int nwc = (int)(ssz / perwin);
  if (nwc > NWIN_TOTAL) nwc = NWIN_TOTAL;
  nwc &= ~31;
  if (nwc < 32) nwc = 32;
  ushort* qd = (ushort*)scratch;
  ushort* kd = qd + (size_t)nwc * 24576;
  ushort* vd = kd + (size_t)nwc * 24576;
  ushort* ao = vd + (size_t)nwc * 24576;
  for (int wc0 = 0; wc0 < NWIN_TOTAL; wc0 += nwc) {
    int nw = (NWIN_TOTAL - wc0 < nwc) ? (NWIN_TOTAL - wc0) : nwc;
    qkv_mfma_k<<<dim3(6, nw / 4), 512, 0, stream>>>(xln, wq, qkv_b, qd, kd,
                                                    vd, wc0);
    attn_k<<<dim3(nw, 6), 128, 0, stream>>>(qd, kd, vd, rpb, ao, wc0);
    proj_mfma_k<<<dim3(2, nw / 4), 512, 0, stream>>>(ao, wp, proj_b, x, out,
                                                     wc0);
  }

  // MLP phase: groups of 256 rows (512 total)
  ln_fused_k<<<ROWS_TOTAL / 4, 256, 0, stream>>>(out, n2g, n2b, xln);
  const size_t pergrp = 786432;  // 256 rows * 1536 * 2B
  int ngc = (int)(ssz / pergrp);
  if (ngc > 512) ngc = 512;
  ngc &= ~7;
  if (ngc < 8) ngc = 8;
  ushort* hm = (ushort*)scratch;
  for (int g0 = 0; g0 < 512; g0 += ngc) {
    int ng = (512 - g0 < ngc) ? (512 - g0) : ngc;
    fc1_mfma_k<<<dim3(8, ng), 512, 0, stream>>>(xln, w1, fc1b, hm, g0 * 256);
    fc2_mfma_k<<<dim3(2, ng), 512, 0, stream>>>(hm, w2, fc2b, out, g0 * 256);
  }
}